// Round 11
// baseline (989.179 us; speedup 1.0000x reference)
//
#include <hip/hip_runtime.h>

constexpr int D = 64;
constexpr int SW = 8;                   // slice width (cols)
constexpr int SL = 8;                   // number of slices
constexpr int BUK_SHIFT = 9;            // 512 dst nodes per bucket
constexpr int BUK_NODES = 1 << BUK_SHIFT;
constexpr int MAX_NBUK = 320;           // supports N <= 163840
constexpr int TILE_E = 4096;            // edges per scatter block (512 thr x 8)

typedef __attribute__((ext_vector_type(8))) short short8;   // 8 bf16 (4 VGPRs)
typedef __attribute__((ext_vector_type(4))) float f32x4;
typedef __attribute__((ext_vector_type(4))) unsigned short ushort4v;

__device__ inline unsigned short f2bf(float f) {   // RNE f32->bf16
    unsigned int u = __float_as_uint(f);
    u += 0x7FFFu + ((u >> 16) & 1u);
    return (unsigned short)(u >> 16);
}
__device__ inline float bf2f(unsigned short s) {
    return __uint_as_float(((unsigned int)s) << 16);
}

// ---------- 1. histogram of coarse buckets (dst >> BUK_SHIFT) ----------
__global__ __launch_bounds__(256) void k_bucket_hist(const int* __restrict__ ei,
                                                     int* __restrict__ bcount,
                                                     int E, int nbuk) {
    __shared__ int h[MAX_NBUK];
    for (int i = threadIdx.x; i < nbuk; i += blockDim.x) h[i] = 0;
    __syncthreads();
    int stride = gridDim.x * blockDim.x;
    for (int e = blockIdx.x * blockDim.x + threadIdx.x; e < E; e += stride)
        atomicAdd(&h[ei[E + e] >> BUK_SHIFT], 1);
    __syncthreads();
    for (int i = threadIdx.x; i < nbuk; i += blockDim.x)
        if (h[i]) atomicAdd(&bcount[i], h[i]);
}

// ---------- 2. scan bucket counts -> bbase; zero gfill; rowptr[N]=E ----------
__global__ __launch_bounds__(512) void k_scan_buckets(const int* __restrict__ bcount,
                                                      int* __restrict__ bbase,
                                                      int* __restrict__ gfill,
                                                      int* __restrict__ rowptr,
                                                      int nbuk, int N, int E) {
    __shared__ int sc[512];
    int tid = threadIdx.x;
    int v = (tid < nbuk) ? bcount[tid] : 0;
    sc[tid] = v;
    __syncthreads();
    for (int off = 1; off < 512; off <<= 1) {
        int t = (tid >= off) ? sc[tid - off] : 0;
        __syncthreads();
        sc[tid] += t;
        __syncthreads();
    }
    if (tid < nbuk) { bbase[tid] = sc[tid] - v; gfill[tid] = 0; }
    if (tid == 0) { bbase[nbuk] = E; rowptr[N] = E; }
}

// ---------- 3. scatter edges into coarse buckets (packed u32) ----------
__global__ __launch_bounds__(512) void k_bucket_scatter(const int* __restrict__ ei,
                                                        const int* __restrict__ bbase,
                                                        int* __restrict__ gfill,
                                                        unsigned int* __restrict__ packed,
                                                        int E, int nbuk) {
    __shared__ int hist[MAX_NBUK], base[MAX_NBUK], fil[MAX_NBUK];
    const int tid = threadIdx.x;
    for (int i = tid; i < nbuk; i += 512) hist[i] = 0;
    __syncthreads();

    const int t0 = blockIdx.x * TILE_E;
    int bk[8];
    unsigned int vv[8];
#pragma unroll
    for (int j = 0; j < 8; ++j) {
        int e = t0 + tid + j * 512;
        bk[j] = -1;
        if (e < E) {
            int src = ei[e];
            int dst = ei[E + e];
            bk[j] = dst >> BUK_SHIFT;
            vv[j] = ((unsigned int)(dst & (BUK_NODES - 1)) << 18) | (unsigned int)src;
            atomicAdd(&hist[bk[j]], 1);
        }
    }
    __syncthreads();
    for (int i = tid; i < nbuk; i += 512) {
        if (hist[i]) base[i] = atomicAdd(&gfill[i], hist[i]);
        fil[i] = 0;
    }
    __syncthreads();
#pragma unroll
    for (int j = 0; j < 8; ++j) {
        if (bk[j] >= 0) {
            int b = bk[j];
            int pos = bbase[b] + base[b] + atomicAdd(&fil[b], 1);
            packed[pos] = vv[j];
        }
    }
}

// ---------- 4. per-bucket: local hist -> rowptr, dinv, ordered csr_src ----------
__global__ __launch_bounds__(256) void k_build_csr(const unsigned int* __restrict__ packed,
                                                   const int* __restrict__ bbase,
                                                   int* __restrict__ rowptr,
                                                   float* __restrict__ dinv,
                                                   int* __restrict__ csr_src,
                                                   int N) {
    __shared__ int hist[BUK_NODES], rp[BUK_NODES], fil[BUK_NODES];
    const int b = blockIdx.x;
    const int s = bbase[b], t = bbase[b + 1];
    const int tid = threadIdx.x;
    for (int i = tid; i < BUK_NODES; i += 256) hist[i] = 0;
    __syncthreads();
    for (int e = s + tid; e < t; e += 256)
        atomicAdd(&hist[packed[e] >> 18], 1);
    __syncthreads();
    if (tid == 0) {
        int run = 0;
        for (int i = 0; i < BUK_NODES; ++i) { rp[i] = run; run += hist[i]; }
    }
    __syncthreads();
    const int dbase = b << BUK_SHIFT;
    for (int ld = tid; ld < BUK_NODES; ld += 256) {
        int d = dbase + ld;
        if (d < N) {
            rowptr[d] = s + rp[ld];
            dinv[d] = rsqrtf((float)(hist[ld] + 1));   // +1 self-loop
        }
        fil[ld] = 0;
    }
    __syncthreads();
    for (int e = s + tid; e < t; e += 256) {
        unsigned int v = packed[e];
        int ld = v >> 18;
        int pos = s + rp[ld] + atomicAdd(&fil[ld], 1);
        csr_src[pos] = (int)(v & 0x3FFFFu);
    }
}

// ------- MFMA GEMM: hs_out(sliced [SL][N][SW]) = bf16((xin @ W)*dinv) -------
template <bool F32IN>
__global__ __launch_bounds__(256) void k_gemm(const float* __restrict__ u,
                                              const float* __restrict__ it,
                                              int U,
                                              const unsigned short* __restrict__ xin_sl,
                                              const float* __restrict__ W,
                                              const float* __restrict__ dinv,
                                              unsigned short* __restrict__ hs_sl,
                                              int N) {
    const int lane = threadIdx.x & 63;
    const int g = lane >> 4;
    const int lr = lane & 15;

    short8 bf[4][2];
#pragma unroll
    for (int ct = 0; ct < 4; ++ct)
#pragma unroll
        for (int kb = 0; kb < 2; ++kb) {
            short8 v;
            int c = ct * 16 + lr;
#pragma unroll
            for (int e = 0; e < 4; ++e) {
                int k0 = kb * 32 + g * 4 + e;
                v[e]     = (short)f2bf(W[k0 * D + c]);
                v[e + 4] = (short)f2bf(W[(k0 + 16) * D + c]);
            }
            bf[ct][kb] = v;
        }

    const int wid = blockIdx.x * (blockDim.x >> 6) + (threadIdx.x >> 6);
    const int nw = gridDim.x * (blockDim.x >> 6);

    for (int rb = wid * 16; rb < N; rb += nw * 16) {
        int row = rb + lr;                     // A-operand row for this lane
        bool ok = (row < N);
        short8 af[2];
        if (F32IN) {
            const float* xr = nullptr;
            if (ok) xr = (row < U) ? (u + (size_t)row * D)
                                   : (it + (size_t)(row - U) * D);
#pragma unroll
            for (int kb = 0; kb < 2; ++kb) {
                float4 q0 = ok ? *(const float4*)(xr + kb * 32 + g * 4)
                               : float4{0.f, 0.f, 0.f, 0.f};
                float4 q1 = ok ? *(const float4*)(xr + kb * 32 + 16 + g * 4)
                               : float4{0.f, 0.f, 0.f, 0.f};
                short8 v;
                v[0] = (short)f2bf(q0.x); v[1] = (short)f2bf(q0.y);
                v[2] = (short)f2bf(q0.z); v[3] = (short)f2bf(q0.w);
                v[4] = (short)f2bf(q1.x); v[5] = (short)f2bf(q1.y);
                v[6] = (short)f2bf(q1.z); v[7] = (short)f2bf(q1.w);
                af[kb] = v;
            }
        } else {
#pragma unroll
            for (int kb = 0; kb < 2; ++kb) {
                int c0 = kb * 32 + g * 4;        // cols c0..c0+3  (within one slice)
                int c1 = c0 + 16;                // cols c1..c1+3
                ushort4v q0 = {0, 0, 0, 0}, q1 = {0, 0, 0, 0};
                if (ok) {
                    q0 = *(const ushort4v*)(xin_sl + (size_t)(c0 >> 3) * N * SW
                                            + (size_t)row * SW + (c0 & 7));
                    q1 = *(const ushort4v*)(xin_sl + (size_t)(c1 >> 3) * N * SW
                                            + (size_t)row * SW + (c1 & 7));
                }
                short8 v;
                v[0] = (short)q0[0]; v[1] = (short)q0[1];
                v[2] = (short)q0[2]; v[3] = (short)q0[3];
                v[4] = (short)q1[0]; v[5] = (short)q1[1];
                v[6] = (short)q1[2]; v[7] = (short)q1[3];
                af[kb] = v;
            }
        }

        float di[4];
#pragma unroll
        for (int r = 0; r < 4; ++r) {
            int ro = rb + g * 4 + r;
            di[r] = (ro < N) ? dinv[ro] : 0.f;
        }

#pragma unroll
        for (int ct = 0; ct < 4; ++ct) {
            f32x4 a = {0.f, 0.f, 0.f, 0.f};
            a = __builtin_amdgcn_mfma_f32_16x16x32_bf16(af[0], bf[ct][0], a, 0, 0, 0);
            a = __builtin_amdgcn_mfma_f32_16x16x32_bf16(af[1], bf[ct][1], a, 0, 0, 0);
            int c = ct * 16 + lr;
            unsigned short* dst = hs_sl + (size_t)(c >> 3) * N * SW + (c & 7);
#pragma unroll
            for (int r = 0; r < 4; ++r) {
                int ro = rb + g * 4 + r;
                if (ro < N) dst[(size_t)ro * SW] = f2bf(a[r] * di[r]);
            }
        }
    }
}

// ------- persistent sliced aggregate: slice epoch outer, L2-resident table -------
// lane = (edge-slot g = lane>>3, col c = lane&7); shfl_xor 8/16/32 reduces slots.
__global__ __launch_bounds__(256, 8) void k_agg_sliced(const int* __restrict__ rowptr,
                                                       const int* __restrict__ csr_src,
                                                       const unsigned short* __restrict__ Xs,
                                                       const float* __restrict__ dinv,
                                                       const float* __restrict__ b,
                                                       unsigned short* __restrict__ Vs,
                                                       int N) {
    const int lane = threadIdx.x & 63;
    const int g = lane >> 3;
    const int c = lane & 7;
    const int gw = (int)((blockIdx.x * (size_t)blockDim.x + threadIdx.x) >> 6);
    const int nw = (gridDim.x * blockDim.x) >> 6;

    for (int s = 0; s < SL; ++s) {
        const unsigned short* T = Xs + (size_t)s * N * SW;
        const float bl = b[s * SW + c];
        for (int row = gw; row < N; row += nw) {
            int beg = rowptr[row], end = rowptr[row + 1];
            float s0 = (g == 0) ? bf2f(T[(size_t)row * SW + c]) : 0.f;  // self-loop
            float s1 = 0.f;
            int e = beg;
            for (; e + 16 <= end; e += 16) {
                int i0 = csr_src[e + g];
                int i1 = csr_src[e + 8 + g];
                s0 += bf2f(T[(size_t)i0 * SW + c]);
                s1 += bf2f(T[(size_t)i1 * SW + c]);
            }
            if (e + 8 <= end) {
                s0 += bf2f(T[(size_t)csr_src[e + g] * SW + c]);
                e += 8;
            }
            int rem = end - e;                 // 0..7
            if (g < rem) s1 += bf2f(T[(size_t)csr_src[e + g] * SW + c]);
            float sum = s0 + s1;
            sum += __shfl_xor(sum, 8);
            sum += __shfl_xor(sum, 16);
            sum += __shfl_xor(sum, 32);
            float val = fmaf(sum, dinv[row], bl);
            if (lane < 8)
                Vs[(size_t)s * N * SW + (size_t)row * SW + c] = f2bf(val);
        }
    }
}

// ------- final: acc[row] = (x0 + v1 + v2 + v3) * 0.25 (wave per row) -------
__global__ __launch_bounds__(256) void k_final(const float* __restrict__ u,
                                               const float* __restrict__ it,
                                               const unsigned short* __restrict__ V1,
                                               const unsigned short* __restrict__ V2,
                                               const unsigned short* __restrict__ V3,
                                               float* __restrict__ acc,
                                               int U, int N) {
    int row = (int)((blockIdx.x * (size_t)blockDim.x + threadIdx.x) >> 6);
    int lane = threadIdx.x & 63;
    if (row >= N) return;
    const float* x0 = (row < U) ? (u + (size_t)row * D)
                                : (it + (size_t)(row - U) * D);
    size_t so = (size_t)(lane >> 3) * N * SW + (size_t)row * SW + (lane & 7);
    float v = x0[lane] + bf2f(V1[so]) + bf2f(V2[so]) + bf2f(V3[so]);
    acc[(size_t)row * D + lane] = v * 0.25f;
}

extern "C" void kernel_launch(void* const* d_in, const int* in_sizes, int n_in,
                              void* d_out, int out_size, void* d_ws, size_t ws_size,
                              hipStream_t stream) {
    const int* ei      = (const int*)d_in[0];
    const float* uemb  = (const float*)d_in[1];
    const float* iemb  = (const float*)d_in[2];
    const float* Ws    = (const float*)d_in[3];
    const float* bs    = (const float*)d_in[4];

    const int E = in_sizes[0] / 2;
    const int U = in_sizes[1] / D;
    const int I = in_sizes[2] / D;
    const int N = U + I;
    const int ND = N * D;
    const int nbuk = (N + BUK_NODES - 1) >> BUK_SHIFT;

    unsigned short* X  = (unsigned short*)d_ws;           // [SL][N][SW] bf16 (hs)
    unsigned short* V1 = X + ND;                          // [SL][N][SW] bf16
    unsigned short* V2 = V1 + ND;                         // [SL][N][SW] bf16
    unsigned short* V3 = V2 + ND;                         // [SL][N][SW] bf16
    float* dinv    = (float*)(V3 + ND);                   // [N]
    int*   csr_src = (int*)(dinv + N);                    // [E]
    unsigned int* packed = (unsigned int*)(csr_src + E);  // [E]
    int*   rowptr  = (int*)(packed + E);                  // [N+1]
    int*   bcount  = rowptr + N + 1;                      // [nbuk]
    int*   bbase   = bcount + MAX_NBUK;                   // [nbuk+1]
    int*   gfill   = bbase + MAX_NBUK + 1;                // [nbuk]

    float* acc = (float*)d_out;                           // [N, D]

    // ---- build CSR ----
    hipMemsetAsync(bcount, 0, nbuk * sizeof(int), stream);
    k_bucket_hist<<<512, 256, 0, stream>>>(ei, bcount, E, nbuk);
    k_scan_buckets<<<1, 512, 0, stream>>>(bcount, bbase, gfill, rowptr, nbuk, N, E);
    k_bucket_scatter<<<(E + TILE_E - 1) / TILE_E, 512, 0, stream>>>(ei, bbase, gfill,
                                                                   packed, E, nbuk);
    k_build_csr<<<nbuk, 256, 0, stream>>>(packed, bbase, rowptr, dinv, csr_src, N);

    // ---- layers (deferred acc, sliced tables) ----
    // gemm0: emb -> X = hs1
    k_gemm<true><<<1024, 256, 0, stream>>>(uemb, iemb, U, nullptr, Ws, dinv, X, N);
    // agg1: X -> V1
    k_agg_sliced<<<2048, 256, 0, stream>>>(rowptr, csr_src, X, dinv, bs, V1, N);
    // gemm1: V1 -> X = hs2
    k_gemm<false><<<1024, 256, 0, stream>>>(nullptr, nullptr, U, V1,
                                            Ws + (size_t)1 * D * D, dinv, X, N);
    // agg2: X -> V2
    k_agg_sliced<<<2048, 256, 0, stream>>>(rowptr, csr_src, X, dinv, bs + D, V2, N);
    // gemm2: V2 -> X = hs3
    k_gemm<false><<<1024, 256, 0, stream>>>(nullptr, nullptr, U, V2,
                                            Ws + (size_t)2 * D * D, dinv, X, N);
    // agg3: X -> V3
    k_agg_sliced<<<2048, 256, 0, stream>>>(rowptr, csr_src, X, dinv, bs + 2 * D, V3, N);
    // final: acc = (x0 + v1 + v2 + v3) / 4
    k_final<<<(N + 3) / 4, 256, 0, stream>>>(uemb, iemb, V1, V2, V3, acc, U, N);
}

// Round 12
// 365.643 us; speedup vs baseline: 2.7053x; 2.7053x over previous
//
#include <hip/hip_runtime.h>

constexpr int D = 64;
constexpr int BUK_SHIFT = 9;            // 512 dst nodes per bucket
constexpr int BUK_NODES = 1 << BUK_SHIFT;
constexpr int MAX_NBUK = 320;           // supports N <= 163840
constexpr int TILE_E = 4096;            // edges per scatter block (512 thr x 8)

typedef __attribute__((ext_vector_type(8))) short short8;   // 8 bf16 (4 VGPRs)
typedef __attribute__((ext_vector_type(4))) float f32x4;

__device__ inline unsigned short f2bf(float f) {   // RNE f32->bf16
    unsigned int u = __float_as_uint(f);
    u += 0x7FFFu + ((u >> 16) & 1u);
    return (unsigned short)(u >> 16);
}
__device__ inline float bf2f(unsigned short s) {
    return __uint_as_float(((unsigned int)s) << 16);
}

// ---------- 1. histogram of coarse buckets (dst >> BUK_SHIFT) ----------
__global__ __launch_bounds__(256) void k_bucket_hist(const int* __restrict__ ei,
                                                     int* __restrict__ bcount,
                                                     int E, int nbuk) {
    __shared__ int h[MAX_NBUK];
    for (int i = threadIdx.x; i < nbuk; i += blockDim.x) h[i] = 0;
    __syncthreads();
    int stride = gridDim.x * blockDim.x;
    for (int e = blockIdx.x * blockDim.x + threadIdx.x; e < E; e += stride)
        atomicAdd(&h[ei[E + e] >> BUK_SHIFT], 1);
    __syncthreads();
    for (int i = threadIdx.x; i < nbuk; i += blockDim.x)
        if (h[i]) atomicAdd(&bcount[i], h[i]);
}

// ---------- 2. scan bucket counts -> bbase; zero gfill; rowptr[N]=E ----------
__global__ __launch_bounds__(512) void k_scan_buckets(const int* __restrict__ bcount,
                                                      int* __restrict__ bbase,
                                                      int* __restrict__ gfill,
                                                      int* __restrict__ rowptr,
                                                      int nbuk, int N, int E) {
    __shared__ int sc[512];
    int tid = threadIdx.x;
    int v = (tid < nbuk) ? bcount[tid] : 0;
    sc[tid] = v;
    __syncthreads();
    for (int off = 1; off < 512; off <<= 1) {
        int t = (tid >= off) ? sc[tid - off] : 0;
        __syncthreads();
        sc[tid] += t;
        __syncthreads();
    }
    if (tid < nbuk) { bbase[tid] = sc[tid] - v; gfill[tid] = 0; }
    if (tid == 0) { bbase[nbuk] = E; rowptr[N] = E; }
}

// ---------- 3. scatter edges into coarse buckets (packed u32) ----------
__global__ __launch_bounds__(512) void k_bucket_scatter(const int* __restrict__ ei,
                                                        const int* __restrict__ bbase,
                                                        int* __restrict__ gfill,
                                                        unsigned int* __restrict__ packed,
                                                        int E, int nbuk) {
    __shared__ int hist[MAX_NBUK], base[MAX_NBUK], fil[MAX_NBUK];
    const int tid = threadIdx.x;
    for (int i = tid; i < nbuk; i += 512) hist[i] = 0;
    __syncthreads();

    const int t0 = blockIdx.x * TILE_E;
    int bk[8];
    unsigned int vv[8];
#pragma unroll
    for (int j = 0; j < 8; ++j) {
        int e = t0 + tid + j * 512;
        bk[j] = -1;
        if (e < E) {
            int src = ei[e];
            int dst = ei[E + e];
            bk[j] = dst >> BUK_SHIFT;
            vv[j] = ((unsigned int)(dst & (BUK_NODES - 1)) << 18) | (unsigned int)src;
            atomicAdd(&hist[bk[j]], 1);
        }
    }
    __syncthreads();
    for (int i = tid; i < nbuk; i += 512) {
        if (hist[i]) base[i] = atomicAdd(&gfill[i], hist[i]);
        fil[i] = 0;
    }
    __syncthreads();
#pragma unroll
    for (int j = 0; j < 8; ++j) {
        if (bk[j] >= 0) {
            int b = bk[j];
            int pos = bbase[b] + base[b] + atomicAdd(&fil[b], 1);
            packed[pos] = vv[j];
        }
    }
}

// ---------- 4. per-bucket: local hist -> rowptr, dinv, ordered csr_src ----------
__global__ __launch_bounds__(256) void k_build_csr(const unsigned int* __restrict__ packed,
                                                   const int* __restrict__ bbase,
                                                   int* __restrict__ rowptr,
                                                   float* __restrict__ dinv,
                                                   int* __restrict__ csr_src,
                                                   int N) {
    __shared__ int hist[BUK_NODES], rp[BUK_NODES], fil[BUK_NODES];
    const int b = blockIdx.x;
    const int s = bbase[b], t = bbase[b + 1];
    const int tid = threadIdx.x;
    for (int i = tid; i < BUK_NODES; i += 256) hist[i] = 0;
    __syncthreads();
    for (int e = s + tid; e < t; e += 256)
        atomicAdd(&hist[packed[e] >> 18], 1);
    __syncthreads();
    if (tid == 0) {
        int run = 0;
        for (int i = 0; i < BUK_NODES; ++i) { rp[i] = run; run += hist[i]; }
    }
    __syncthreads();
    const int dbase = b << BUK_SHIFT;
    for (int ld = tid; ld < BUK_NODES; ld += 256) {
        int d = dbase + ld;
        if (d < N) {
            rowptr[d] = s + rp[ld];
            dinv[d] = rsqrtf((float)(hist[ld] + 1));   // +1 self-loop
        }
        fil[ld] = 0;
    }
    __syncthreads();
    for (int e = s + tid; e < t; e += 256) {
        unsigned int v = packed[e];
        int ld = v >> 18;
        int pos = s + rp[ld] + atomicAdd(&fil[ld], 1);
        csr_src[pos] = (int)(v & 0x3FFFFu);
    }
}

// ------- MFMA GEMM: hs_out = bf16((xin @ W)*dinv) -------
template <bool F32IN>
__global__ __launch_bounds__(256) void k_gemm(const float* __restrict__ u,
                                              const float* __restrict__ it,
                                              int U,
                                              const unsigned short* __restrict__ xin16,
                                              const float* __restrict__ W,
                                              const float* __restrict__ dinv,
                                              unsigned short* __restrict__ hs_out,
                                              int N) {
    const int lane = threadIdx.x & 63;
    const int g = lane >> 4;
    const int lr = lane & 15;

    short8 bf[4][2];
#pragma unroll
    for (int ct = 0; ct < 4; ++ct)
#pragma unroll
        for (int kb = 0; kb < 2; ++kb) {
            short8 v;
            int c = ct * 16 + lr;
#pragma unroll
            for (int e = 0; e < 4; ++e) {
                int k0 = kb * 32 + g * 4 + e;
                v[e]     = (short)f2bf(W[k0 * D + c]);
                v[e + 4] = (short)f2bf(W[(k0 + 16) * D + c]);
            }
            bf[ct][kb] = v;
        }

    const int wid = blockIdx.x * (blockDim.x >> 6) + (threadIdx.x >> 6);
    const int nw = gridDim.x * (blockDim.x >> 6);

    for (int rb = wid * 16; rb < N; rb += nw * 16) {
        int row = rb + lr;                     // A-operand row for this lane
        bool ok = (row < N);
        short8 af[2];
        if (F32IN) {
            const float* xr = nullptr;
            if (ok) xr = (row < U) ? (u + (size_t)row * D)
                                   : (it + (size_t)(row - U) * D);
#pragma unroll
            for (int kb = 0; kb < 2; ++kb) {
                float4 q0 = ok ? *(const float4*)(xr + kb * 32 + g * 4)
                               : float4{0.f, 0.f, 0.f, 0.f};
                float4 q1 = ok ? *(const float4*)(xr + kb * 32 + 16 + g * 4)
                               : float4{0.f, 0.f, 0.f, 0.f};
                short8 v;
                v[0] = (short)f2bf(q0.x); v[1] = (short)f2bf(q0.y);
                v[2] = (short)f2bf(q0.z); v[3] = (short)f2bf(q0.w);
                v[4] = (short)f2bf(q1.x); v[5] = (short)f2bf(q1.y);
                v[6] = (short)f2bf(q1.z); v[7] = (short)f2bf(q1.w);
                af[kb] = v;
            }
        } else {
            const unsigned short* xr = xin16 + (size_t)row * D;
#pragma unroll
            for (int kb = 0; kb < 2; ++kb) {
                short4 q0 = ok ? *(const short4*)(xr + kb * 32 + g * 4)
                               : short4{0, 0, 0, 0};
                short4 q1 = ok ? *(const short4*)(xr + kb * 32 + 16 + g * 4)
                               : short4{0, 0, 0, 0};
                short8 v;
                v[0] = q0.x; v[1] = q0.y; v[2] = q0.z; v[3] = q0.w;
                v[4] = q1.x; v[5] = q1.y; v[6] = q1.z; v[7] = q1.w;
                af[kb] = v;
            }
        }

        float di[4];
#pragma unroll
        for (int r = 0; r < 4; ++r) {
            int ro = rb + g * 4 + r;
            di[r] = (ro < N) ? dinv[ro] : 0.f;
        }

#pragma unroll
        for (int ct = 0; ct < 4; ++ct) {
            f32x4 a = {0.f, 0.f, 0.f, 0.f};
            a = __builtin_amdgcn_mfma_f32_16x16x32_bf16(af[0], bf[ct][0], a, 0, 0, 0);
            a = __builtin_amdgcn_mfma_f32_16x16x32_bf16(af[1], bf[ct][1], a, 0, 0, 0);
#pragma unroll
            for (int r = 0; r < 4; ++r) {
                int ro = rb + g * 4 + r;
                if (ro < N)
                    hs_out[(size_t)ro * D + ct * 16 + lr] = f2bf(a[r] * di[r]);
            }
        }
    }
}

// ------- aggregate, pair-packed gathers: 32 lanes cover a row, 2 edges/instr -------
// lane = (half = lane>>5 owns even/odd edges; li = lane&31 owns cols 2li, 2li+1)
// !LAST: val16[w] = bf16(dinv*(hs[w]+sum hs[src]) + b)
//  LAST: acc[w] = (x0 + v1 + v2 + val3) * 0.25
template <bool LAST>
__global__ __launch_bounds__(256) void k_aggregate(const int* __restrict__ rowptr,
                                                   const int* __restrict__ csr_src,
                                                   const unsigned short* __restrict__ hs16,
                                                   const float* __restrict__ dinv,
                                                   const float* __restrict__ b,
                                                   unsigned short* __restrict__ val16,
                                                   const float* __restrict__ u,
                                                   const float* __restrict__ it,
                                                   int U,
                                                   const unsigned short* __restrict__ V1,
                                                   const unsigned short* __restrict__ V2,
                                                   float* __restrict__ acc,
                                                   int N) {
    int w = (int)((blockIdx.x * (size_t)blockDim.x + threadIdx.x) >> 6);
    int lane = threadIdx.x & 63;
    if (w >= N) return;
    const int half = lane >> 5;
    const int li = lane & 31;
    const unsigned int* T = (const unsigned int*)hs16;   // 32 uints (2 cols) per row
    int beg = rowptr[w], end = rowptr[w + 1];
    const float di = dinv[w];

    float aLo[4] = {0.f, 0.f, 0.f, 0.f};
    float aHi[4] = {0.f, 0.f, 0.f, 0.f};
    if (half == 0) {   // self-loop (hs already * dinv[src])
        unsigned int v = T[(size_t)w * 32 + li];
        aLo[0] += __uint_as_float(v << 16);
        aHi[0] += __uint_as_float(v & 0xffff0000u);
    }

    int e = beg;
    for (; e + 16 <= end; e += 16) {       // 8 gathers in flight, 16 edges
        int idx[8];
#pragma unroll
        for (int j = 0; j < 8; ++j) idx[j] = csr_src[e + 2 * j + half];
        unsigned int g[8];
#pragma unroll
        for (int j = 0; j < 8; ++j) g[j] = T[(size_t)idx[j] * 32 + li];
#pragma unroll
        for (int j = 0; j < 8; ++j) {
            aLo[j & 3] += __uint_as_float(g[j] << 16);
            aHi[j & 3] += __uint_as_float(g[j] & 0xffff0000u);
        }
    }
    if (e + 8 <= end) {
        int idx[4];
#pragma unroll
        for (int j = 0; j < 4; ++j) idx[j] = csr_src[e + 2 * j + half];
        unsigned int g[4];
#pragma unroll
        for (int j = 0; j < 4; ++j) g[j] = T[(size_t)idx[j] * 32 + li];
#pragma unroll
        for (int j = 0; j < 4; ++j) {
            aLo[j] += __uint_as_float(g[j] << 16);
            aHi[j] += __uint_as_float(g[j] & 0xffff0000u);
        }
        e += 8;
    }
    for (int t2 = e + half; t2 < end; t2 += 2) {   // tail: parity split
        unsigned int g = T[(size_t)csr_src[t2] * 32 + li];
        aLo[0] += __uint_as_float(g << 16);
        aHi[0] += __uint_as_float(g & 0xffff0000u);
    }

    float sLo = (aLo[0] + aLo[1]) + (aLo[2] + aLo[3]);
    float sHi = (aHi[0] + aHi[1]) + (aHi[2] + aHi[3]);
    sLo += __shfl_xor(sLo, 32);
    sHi += __shfl_xor(sHi, 32);

    if (half == 0) {
        float2 bb = *(const float2*)(b + 2 * li);
        float vLo = fmaf(sLo, di, bb.x);
        float vHi = fmaf(sHi, di, bb.y);
        if (LAST) {
            const float* x0 = (w < U) ? (u + (size_t)w * D)
                                      : (it + (size_t)(w - U) * D);
            float2 x = *(const float2*)(x0 + 2 * li);
            unsigned int p1 = ((const unsigned int*)V1)[(size_t)w * 32 + li];
            unsigned int p2 = ((const unsigned int*)V2)[(size_t)w * 32 + li];
            float o0 = (x.x + __uint_as_float(p1 << 16)
                            + __uint_as_float(p2 << 16) + vLo) * 0.25f;
            float o1 = (x.y + __uint_as_float(p1 & 0xffff0000u)
                            + __uint_as_float(p2 & 0xffff0000u) + vHi) * 0.25f;
            *(float2*)(acc + (size_t)w * D + 2 * li) = float2{o0, o1};
        } else {
            unsigned int pk = ((unsigned int)f2bf(vHi) << 16) | (unsigned int)f2bf(vLo);
            ((unsigned int*)val16)[(size_t)w * 32 + li] = pk;
        }
    }
}

extern "C" void kernel_launch(void* const* d_in, const int* in_sizes, int n_in,
                              void* d_out, int out_size, void* d_ws, size_t ws_size,
                              hipStream_t stream) {
    const int* ei      = (const int*)d_in[0];
    const float* uemb  = (const float*)d_in[1];
    const float* iemb  = (const float*)d_in[2];
    const float* Ws    = (const float*)d_in[3];
    const float* bs    = (const float*)d_in[4];

    const int E = in_sizes[0] / 2;
    const int U = in_sizes[1] / D;
    const int I = in_sizes[2] / D;
    const int N = U + I;
    const int ND = N * D;
    const int nbuk = (N + BUK_NODES - 1) >> BUK_SHIFT;

    unsigned short* X  = (unsigned short*)d_ws;           // [N, D] bf16 (hs, reused)
    unsigned short* V1 = X + ND;                          // [N, D] bf16
    unsigned short* V2 = V1 + ND;                         // [N, D] bf16
    float* dinv    = (float*)(V2 + ND);                   // [N]
    int*   csr_src = (int*)(dinv + N);                    // [E]
    unsigned int* packed = (unsigned int*)(csr_src + E);  // [E]
    int*   rowptr  = (int*)(packed + E);                  // [N+1]
    int*   bcount  = rowptr + N + 1;                      // [nbuk]
    int*   bbase   = bcount + MAX_NBUK;                   // [nbuk+1]
    int*   gfill   = bbase + MAX_NBUK + 1;                // [nbuk]

    float* acc = (float*)d_out;                           // [N, D]

    // ---- build CSR ----
    hipMemsetAsync(bcount, 0, nbuk * sizeof(int), stream);
    k_bucket_hist<<<512, 256, 0, stream>>>(ei, bcount, E, nbuk);
    k_scan_buckets<<<1, 512, 0, stream>>>(bcount, bbase, gfill, rowptr, nbuk, N, E);
    k_bucket_scatter<<<(E + TILE_E - 1) / TILE_E, 512, 0, stream>>>(ei, bbase, gfill,
                                                                   packed, E, nbuk);
    k_build_csr<<<nbuk, 256, 0, stream>>>(packed, bbase, rowptr, dinv, csr_src, N);

    // ---- layers (deferred acc; final fused into agg3) ----
    const int nagg = (N + 3) / 4;
    // gemm0: emb -> X = hs1
    k_gemm<true><<<1024, 256, 0, stream>>>(uemb, iemb, U, nullptr, Ws, dinv, X, N);
    // agg1: X -> V1
    k_aggregate<false><<<nagg, 256, 0, stream>>>(rowptr, csr_src, X, dinv, bs, V1,
                                                 nullptr, nullptr, U, nullptr, nullptr,
                                                 nullptr, N);
    // gemm1: V1 -> X = hs2
    k_gemm<false><<<1024, 256, 0, stream>>>(nullptr, nullptr, U, V1,
                                            Ws + (size_t)1 * D * D, dinv, X, N);
    // agg2: X -> V2
    k_aggregate<false><<<nagg, 256, 0, stream>>>(rowptr, csr_src, X, dinv, bs + D, V2,
                                                 nullptr, nullptr, U, nullptr, nullptr,
                                                 nullptr, N);
    // gemm2: V2 -> X = hs3
    k_gemm<false><<<1024, 256, 0, stream>>>(nullptr, nullptr, U, V2,
                                            Ws + (size_t)2 * D * D, dinv, X, N);
    // agg3 (fused final): acc = (x0 + v1 + v2 + val3) / 4
    k_aggregate<true><<<nagg, 256, 0, stream>>>(rowptr, csr_src, X, dinv, bs + 2 * D,
                                                nullptr, uemb, iemb, U, V1, V2, acc, N);
}

// Round 13
// 347.643 us; speedup vs baseline: 2.8454x; 1.0518x over previous
//
#include <hip/hip_runtime.h>

constexpr int D = 64;
constexpr int BUK_SHIFT = 9;            // 512 dst nodes per bucket
constexpr int BUK_NODES = 1 << BUK_SHIFT;
constexpr int MAX_NBUK = 320;           // supports N <= 163840
constexpr int TILE_E = 4096;            // edges per scatter block (512 thr x 8)

typedef __attribute__((ext_vector_type(8))) short short8;   // 8 bf16 (4 VGPRs)
typedef __attribute__((ext_vector_type(4))) float f32x4;

__device__ inline unsigned short f2bf(float f) {   // RNE f32->bf16
    unsigned int u = __float_as_uint(f);
    u += 0x7FFFu + ((u >> 16) & 1u);
    return (unsigned short)(u >> 16);
}
__device__ inline float bf2f(unsigned short s) {
    return __uint_as_float(((unsigned int)s) << 16);
}
__device__ inline float ub0(unsigned int q) { return (float)(q & 0xffu); }
__device__ inline float ub1(unsigned int q) { return (float)((q >> 8) & 0xffu); }
__device__ inline float ub2(unsigned int q) { return (float)((q >> 16) & 0xffu); }
__device__ inline float ub3(unsigned int q) { return (float)(q >> 24); }

// ---------- 1. histogram of coarse buckets (dst >> BUK_SHIFT) ----------
__global__ __launch_bounds__(256) void k_bucket_hist(const int* __restrict__ ei,
                                                     int* __restrict__ bcount,
                                                     int E, int nbuk) {
    __shared__ int h[MAX_NBUK];
    for (int i = threadIdx.x; i < nbuk; i += blockDim.x) h[i] = 0;
    __syncthreads();
    int stride = gridDim.x * blockDim.x;
    for (int e = blockIdx.x * blockDim.x + threadIdx.x; e < E; e += stride)
        atomicAdd(&h[ei[E + e] >> BUK_SHIFT], 1);
    __syncthreads();
    for (int i = threadIdx.x; i < nbuk; i += blockDim.x)
        if (h[i]) atomicAdd(&bcount[i], h[i]);
}

// ---------- 2. scan bucket counts -> bbase; zero gfill; rowptr[N]=E ----------
__global__ __launch_bounds__(512) void k_scan_buckets(const int* __restrict__ bcount,
                                                      int* __restrict__ bbase,
                                                      int* __restrict__ gfill,
                                                      int* __restrict__ rowptr,
                                                      int nbuk, int N, int E) {
    __shared__ int sc[512];
    int tid = threadIdx.x;
    int v = (tid < nbuk) ? bcount[tid] : 0;
    sc[tid] = v;
    __syncthreads();
    for (int off = 1; off < 512; off <<= 1) {
        int t = (tid >= off) ? sc[tid - off] : 0;
        __syncthreads();
        sc[tid] += t;
        __syncthreads();
    }
    if (tid < nbuk) { bbase[tid] = sc[tid] - v; gfill[tid] = 0; }
    if (tid == 0) { bbase[nbuk] = E; rowptr[N] = E; }
}

// ---------- 3. scatter edges into coarse buckets (packed u32) ----------
__global__ __launch_bounds__(512) void k_bucket_scatter(const int* __restrict__ ei,
                                                        const int* __restrict__ bbase,
                                                        int* __restrict__ gfill,
                                                        unsigned int* __restrict__ packed,
                                                        int E, int nbuk) {
    __shared__ int hist[MAX_NBUK], base[MAX_NBUK], fil[MAX_NBUK];
    const int tid = threadIdx.x;
    for (int i = tid; i < nbuk; i += 512) hist[i] = 0;
    __syncthreads();

    const int t0 = blockIdx.x * TILE_E;
    int bk[8];
    unsigned int vv[8];
#pragma unroll
    for (int j = 0; j < 8; ++j) {
        int e = t0 + tid + j * 512;
        bk[j] = -1;
        if (e < E) {
            int src = ei[e];
            int dst = ei[E + e];
            bk[j] = dst >> BUK_SHIFT;
            vv[j] = ((unsigned int)(dst & (BUK_NODES - 1)) << 18) | (unsigned int)src;
            atomicAdd(&hist[bk[j]], 1);
        }
    }
    __syncthreads();
    for (int i = tid; i < nbuk; i += 512) {
        if (hist[i]) base[i] = atomicAdd(&gfill[i], hist[i]);
        fil[i] = 0;
    }
    __syncthreads();
#pragma unroll
    for (int j = 0; j < 8; ++j) {
        if (bk[j] >= 0) {
            int b = bk[j];
            int pos = bbase[b] + base[b] + atomicAdd(&fil[b], 1);
            packed[pos] = vv[j];
        }
    }
}

// ---------- 4. per-bucket: local hist -> rowptr, dinv, ordered csr_src ----------
__global__ __launch_bounds__(256) void k_build_csr(const unsigned int* __restrict__ packed,
                                                   const int* __restrict__ bbase,
                                                   int* __restrict__ rowptr,
                                                   float* __restrict__ dinv,
                                                   int* __restrict__ csr_src,
                                                   int N) {
    __shared__ int hist[BUK_NODES], rp[BUK_NODES], fil[BUK_NODES];
    const int b = blockIdx.x;
    const int s = bbase[b], t = bbase[b + 1];
    const int tid = threadIdx.x;
    for (int i = tid; i < BUK_NODES; i += 256) hist[i] = 0;
    __syncthreads();
    for (int e = s + tid; e < t; e += 256)
        atomicAdd(&hist[packed[e] >> 18], 1);
    __syncthreads();
    if (tid == 0) {
        int run = 0;
        for (int i = 0; i < BUK_NODES; ++i) { rp[i] = run; run += hist[i]; }
    }
    __syncthreads();
    const int dbase = b << BUK_SHIFT;
    for (int ld = tid; ld < BUK_NODES; ld += 256) {
        int d = dbase + ld;
        if (d < N) {
            rowptr[d] = s + rp[ld];
            dinv[d] = rsqrtf((float)(hist[ld] + 1));   // +1 self-loop
        }
        fil[ld] = 0;
    }
    __syncthreads();
    for (int e = s + tid; e < t; e += 256) {
        unsigned int v = packed[e];
        int ld = v >> 18;
        int pos = s + rp[ld] + atomicAdd(&fil[ld], 1);
        csr_src[pos] = (int)(v & 0x3FFFFu);
    }
}

// ------- MFMA GEMM: X8 = int8((xin @ W)*dinv), per-16-row-tile scale in S -------
template <bool F32IN>
__global__ __launch_bounds__(256) void k_gemm(const float* __restrict__ u,
                                              const float* __restrict__ it,
                                              int U,
                                              const unsigned short* __restrict__ xin16,
                                              const float* __restrict__ W,
                                              const float* __restrict__ dinv,
                                              unsigned char* __restrict__ X8,
                                              float* __restrict__ S,
                                              int N) {
    const int lane = threadIdx.x & 63;
    const int g = lane >> 4;
    const int lr = lane & 15;

    short8 bf[4][2];
#pragma unroll
    for (int ct = 0; ct < 4; ++ct)
#pragma unroll
        for (int kb = 0; kb < 2; ++kb) {
            short8 v;
            int c = ct * 16 + lr;
#pragma unroll
            for (int e = 0; e < 4; ++e) {
                int k0 = kb * 32 + g * 4 + e;
                v[e]     = (short)f2bf(W[k0 * D + c]);
                v[e + 4] = (short)f2bf(W[(k0 + 16) * D + c]);
            }
            bf[ct][kb] = v;
        }

    const int wid = blockIdx.x * (blockDim.x >> 6) + (threadIdx.x >> 6);
    const int nw = gridDim.x * (blockDim.x >> 6);

    for (int rb = wid * 16; rb < N; rb += nw * 16) {
        int row = rb + lr;                     // A-operand row for this lane
        bool ok = (row < N);
        short8 af[2];
        if (F32IN) {
            const float* xr = nullptr;
            if (ok) xr = (row < U) ? (u + (size_t)row * D)
                                   : (it + (size_t)(row - U) * D);
#pragma unroll
            for (int kb = 0; kb < 2; ++kb) {
                float4 q0 = ok ? *(const float4*)(xr + kb * 32 + g * 4)
                               : float4{0.f, 0.f, 0.f, 0.f};
                float4 q1 = ok ? *(const float4*)(xr + kb * 32 + 16 + g * 4)
                               : float4{0.f, 0.f, 0.f, 0.f};
                short8 v;
                v[0] = (short)f2bf(q0.x); v[1] = (short)f2bf(q0.y);
                v[2] = (short)f2bf(q0.z); v[3] = (short)f2bf(q0.w);
                v[4] = (short)f2bf(q1.x); v[5] = (short)f2bf(q1.y);
                v[6] = (short)f2bf(q1.z); v[7] = (short)f2bf(q1.w);
                af[kb] = v;
            }
        } else {
            const unsigned short* xr = xin16 + (size_t)row * D;
#pragma unroll
            for (int kb = 0; kb < 2; ++kb) {
                short4 q0 = ok ? *(const short4*)(xr + kb * 32 + g * 4)
                               : short4{0, 0, 0, 0};
                short4 q1 = ok ? *(const short4*)(xr + kb * 32 + 16 + g * 4)
                               : short4{0, 0, 0, 0};
                short8 v;
                v[0] = q0.x; v[1] = q0.y; v[2] = q0.z; v[3] = q0.w;
                v[4] = q1.x; v[5] = q1.y; v[6] = q1.z; v[7] = q1.w;
                af[kb] = v;
            }
        }

        float di[4];
#pragma unroll
        for (int r = 0; r < 4; ++r) {
            int ro = rb + g * 4 + r;
            di[r] = (ro < N) ? dinv[ro] : 0.f;
        }

        float vals[4][4];
        float mx = 0.f;
#pragma unroll
        for (int ct = 0; ct < 4; ++ct) {
            f32x4 a = {0.f, 0.f, 0.f, 0.f};
            a = __builtin_amdgcn_mfma_f32_16x16x32_bf16(af[0], bf[ct][0], a, 0, 0, 0);
            a = __builtin_amdgcn_mfma_f32_16x16x32_bf16(af[1], bf[ct][1], a, 0, 0, 0);
#pragma unroll
            for (int r = 0; r < 4; ++r) {
                float v = a[r] * di[r];
                vals[ct][r] = v;
                mx = fmaxf(mx, fabsf(v));
            }
        }
#pragma unroll
        for (int off = 32; off > 0; off >>= 1)
            mx = fmaxf(mx, __shfl_xor(mx, off));
        mx = fmaxf(mx, 1e-30f);
        const float sinv = 127.0f / mx;
        if (lane == 0) S[rb >> 4] = mx * (1.0f / 127.0f);
#pragma unroll
        for (int ct = 0; ct < 4; ++ct)
#pragma unroll
            for (int r = 0; r < 4; ++r) {
                int ro = rb + g * 4 + r;
                if (ro < N)
                    X8[(size_t)ro * D + ct * 16 + lr] =
                        (unsigned char)(int)(rintf(vals[ct][r] * sinv) + 128.f);
            }
    }
}

// ------- aggregate, int8 gathers: 16 lanes x 4 cols per edge, 4 edges/instr -------
// lane = (edge slot es = lane>>4, lc = lane&15 owns cols 4lc..4lc+3)
// !LAST: val16[w] = bf16(dinv*(hs[w]+sum hs[src]) + b)
//  LAST: acc[w] = (x0 + v1 + v2 + val3) * 0.25
template <bool LAST>
__global__ __launch_bounds__(256) void k_aggregate(const int* __restrict__ rowptr,
                                                   const int* __restrict__ csr_src,
                                                   const unsigned char* __restrict__ X8,
                                                   const float* __restrict__ S,
                                                   const float* __restrict__ dinv,
                                                   const float* __restrict__ b,
                                                   unsigned short* __restrict__ val16,
                                                   const float* __restrict__ u,
                                                   const float* __restrict__ it,
                                                   int U,
                                                   const unsigned short* __restrict__ V1,
                                                   const unsigned short* __restrict__ V2,
                                                   float* __restrict__ acc,
                                                   int N) {
    int w = (int)((blockIdx.x * (size_t)blockDim.x + threadIdx.x) >> 6);
    int lane = threadIdx.x & 63;
    if (w >= N) return;
    const int es = lane >> 4;
    const int lc = lane & 15;
    const unsigned int* Q = (const unsigned int*)X8;   // 16 uints (4 cols each) per row
    int beg = rowptr[w], end = rowptr[w + 1];
    const float di = dinv[w];

    float a0 = 0.f, a1 = 0.f, a2 = 0.f, a3 = 0.f, as = 0.f;
    if (es == 0) {   // self-loop (hs already * dinv[src])
        unsigned int q = Q[(size_t)w * 16 + lc];
        float s = S[w >> 4];
        a0 = fmaf(ub0(q), s, a0); a1 = fmaf(ub1(q), s, a1);
        a2 = fmaf(ub2(q), s, a2); a3 = fmaf(ub3(q), s, a3);
        as += s;
    }

    int e = beg;
    for (; e + 16 <= end; e += 16) {       // 4 row-gathers in flight per lane
        int idx[4];
#pragma unroll
        for (int j = 0; j < 4; ++j) idx[j] = csr_src[e + 4 * j + es];
        unsigned int q[4];
#pragma unroll
        for (int j = 0; j < 4; ++j) q[j] = Q[(size_t)idx[j] * 16 + lc];
        float s[4];
#pragma unroll
        for (int j = 0; j < 4; ++j) s[j] = S[idx[j] >> 4];
#pragma unroll
        for (int j = 0; j < 4; ++j) {
            a0 = fmaf(ub0(q[j]), s[j], a0);
            a1 = fmaf(ub1(q[j]), s[j], a1);
            a2 = fmaf(ub2(q[j]), s[j], a2);
            a3 = fmaf(ub3(q[j]), s[j], a3);
            as += s[j];
        }
    }
    for (; e + 4 <= end; e += 4) {
        int idx = csr_src[e + es];
        unsigned int q = Q[(size_t)idx * 16 + lc];
        float s = S[idx >> 4];
        a0 = fmaf(ub0(q), s, a0); a1 = fmaf(ub1(q), s, a1);
        a2 = fmaf(ub2(q), s, a2); a3 = fmaf(ub3(q), s, a3);
        as += s;
    }
    int rem = end - e;                     // 0..3
    if (es < rem) {
        int idx = csr_src[e + es];
        unsigned int q = Q[(size_t)idx * 16 + lc];
        float s = S[idx >> 4];
        a0 = fmaf(ub0(q), s, a0); a1 = fmaf(ub1(q), s, a1);
        a2 = fmaf(ub2(q), s, a2); a3 = fmaf(ub3(q), s, a3);
        as += s;
    }

    // remove the +128 bias, then reduce across the 4 edge slots
    const float bias128 = 128.f * as;
    a0 -= bias128; a1 -= bias128; a2 -= bias128; a3 -= bias128;
#pragma unroll
    for (int off = 16; off <= 32; off <<= 1) {
        a0 += __shfl_xor(a0, off);
        a1 += __shfl_xor(a1, off);
        a2 += __shfl_xor(a2, off);
        a3 += __shfl_xor(a3, off);
    }

    if (es == 0) {
        float4 bb = *(const float4*)(b + 4 * lc);
        float v0 = fmaf(a0, di, bb.x);
        float v1 = fmaf(a1, di, bb.y);
        float v2 = fmaf(a2, di, bb.z);
        float v3 = fmaf(a3, di, bb.w);
        if (LAST) {
            const float* x0 = (w < U) ? (u + (size_t)w * D)
                                      : (it + (size_t)(w - U) * D);
            float4 x = *(const float4*)(x0 + 4 * lc);
            ushort4 p1 = *(const ushort4*)(V1 + (size_t)w * D + 4 * lc);
            ushort4 p2 = *(const ushort4*)(V2 + (size_t)w * D + 4 * lc);
            float4 o;
            o.x = (x.x + bf2f(p1.x) + bf2f(p2.x) + v0) * 0.25f;
            o.y = (x.y + bf2f(p1.y) + bf2f(p2.y) + v1) * 0.25f;
            o.z = (x.z + bf2f(p1.z) + bf2f(p2.z) + v2) * 0.25f;
            o.w = (x.w + bf2f(p1.w) + bf2f(p2.w) + v3) * 0.25f;
            *(float4*)(acc + (size_t)w * D + 4 * lc) = o;
        } else {
            ushort4 pk;
            pk.x = f2bf(v0); pk.y = f2bf(v1); pk.z = f2bf(v2); pk.w = f2bf(v3);
            *(ushort4*)(val16 + (size_t)w * D + 4 * lc) = pk;
        }
    }
}

extern "C" void kernel_launch(void* const* d_in, const int* in_sizes, int n_in,
                              void* d_out, int out_size, void* d_ws, size_t ws_size,
                              hipStream_t stream) {
    const int* ei      = (const int*)d_in[0];
    const float* uemb  = (const float*)d_in[1];
    const float* iemb  = (const float*)d_in[2];
    const float* Ws    = (const float*)d_in[3];
    const float* bs    = (const float*)d_in[4];

    const int E = in_sizes[0] / 2;
    const int U = in_sizes[1] / D;
    const int I = in_sizes[2] / D;
    const int N = U + I;
    const int ND = N * D;
    const int nbuk = (N + BUK_NODES - 1) >> BUK_SHIFT;
    const int NT = (N + 15) / 16;

    unsigned char* X8 = (unsigned char*)d_ws;             // [N, D] int8 (hs, reused)
    float* S = (float*)(X8 + ND);                         // [NT] tile scales (pad to 8B)
    unsigned short* V1 = (unsigned short*)(S + ((NT + 1) & ~1)); // [N, D] bf16
    unsigned short* V2 = V1 + ND;                         // [N, D] bf16
    float* dinv    = (float*)(V2 + ND);                   // [N]
    int*   csr_src = (int*)(dinv + N);                    // [E]
    unsigned int* packed = (unsigned int*)(csr_src + E);  // [E]
    int*   rowptr  = (int*)(packed + E);                  // [N+1]
    int*   bcount  = rowptr + N + 1;                      // [nbuk]
    int*   bbase   = bcount + MAX_NBUK;                   // [nbuk+1]
    int*   gfill   = bbase + MAX_NBUK + 1;                // [nbuk]

    float* acc = (float*)d_out;                           // [N, D]

    // ---- build CSR ----
    hipMemsetAsync(bcount, 0, nbuk * sizeof(int), stream);
    k_bucket_hist<<<512, 256, 0, stream>>>(ei, bcount, E, nbuk);
    k_scan_buckets<<<1, 512, 0, stream>>>(bcount, bbase, gfill, rowptr, nbuk, N, E);
    k_bucket_scatter<<<(E + TILE_E - 1) / TILE_E, 512, 0, stream>>>(ei, bbase, gfill,
                                                                   packed, E, nbuk);
    k_build_csr<<<nbuk, 256, 0, stream>>>(packed, bbase, rowptr, dinv, csr_src, N);

    // ---- layers (deferred acc; final fused into agg3) ----
    const int nagg = (N + 3) / 4;
    // gemm0: emb -> X8 = hs1 (int8 + S)
    k_gemm<true><<<1024, 256, 0, stream>>>(uemb, iemb, U, nullptr, Ws, dinv, X8, S, N);
    // agg1: X8 -> V1
    k_aggregate<false><<<nagg, 256, 0, stream>>>(rowptr, csr_src, X8, S, dinv, bs, V1,
                                                 nullptr, nullptr, U, nullptr, nullptr,
                                                 nullptr, N);
    // gemm1: V1 -> X8 = hs2
    k_gemm<false><<<1024, 256, 0, stream>>>(nullptr, nullptr, U, V1,
                                            Ws + (size_t)1 * D * D, dinv, X8, S, N);
    // agg2: X8 -> V2
    k_aggregate<false><<<nagg, 256, 0, stream>>>(rowptr, csr_src, X8, S, dinv, bs + D, V2,
                                                 nullptr, nullptr, U, nullptr, nullptr,
                                                 nullptr, N);
    // gemm2: V2 -> X8 = hs3
    k_gemm<false><<<1024, 256, 0, stream>>>(nullptr, nullptr, U, V2,
                                            Ws + (size_t)2 * D * D, dinv, X8, S, N);
    // agg3 (fused final): acc = (x0 + v1 + v2 + val3) / 4
    k_aggregate<true><<<nagg, 256, 0, stream>>>(rowptr, csr_src, X8, S, dinv, bs + 2 * D,
                                                nullptr, uemb, iemb, U, V1, V2, acc, N);
}